// Round 11
// baseline (336.876 us; speedup 1.0000x reference)
//
#include <hip/hip_runtime.h>
#include <hip/hip_bf16.h>

#define NFEAT 128

typedef __attribute__((ext_vector_type(8))) short frag8;
typedef __attribute__((ext_vector_type(4))) float f32x4;

__device__ __forceinline__ unsigned short f2bf(float f) {
  unsigned int u = __builtin_bit_cast(unsigned int, f);
  u += 0x7fffu + ((u >> 16) & 1u);
  return (unsigned short)(u >> 16);
}
__device__ __forceinline__ unsigned int pack2(float lo, float hi) {
  return (unsigned int)f2bf(lo) | ((unsigned int)f2bf(hi) << 16);
}
// accumulate 2 packed bf16: lo exact; hi uses raw bits (low 16 bits are a
// <=2^-8-relative mantissa perturbation, below the bf16 rounding already present)
__device__ __forceinline__ void acc_pair(float* acc, unsigned int u) {
  acc[0] += __builtin_bit_cast(float, u << 16);
  acc[1] += __builtin_bit_cast(float, u);
}
__device__ __forceinline__ void acc_uint4(float* a, const uint4& f) {
  acc_pair(a + 0, f.x);
  acc_pair(a + 2, f.y);
  acc_pair(a + 4, f.z);
  acc_pair(a + 6, f.w);
}

// ================= CSR build: two-level bucketed counting sort =================
__global__ __launch_bounds__(256) void k_bucket_count(
    const int* __restrict__ dst, int* __restrict__ bucket_cnt, int E, int NB, int chunk) {
  __shared__ int hist[512];
  int t = threadIdx.x;
  hist[t] = 0;
  hist[t + 256] = 0;
  __syncthreads();
  int beg = blockIdx.x * chunk, end = min(beg + chunk, E);
  for (int i = beg + t; i < end; i += 256) atomicAdd(&hist[dst[i] >> 8], 1);
  __syncthreads();
  for (int k = t; k < NB; k += 256)
    if (hist[k]) atomicAdd(&bucket_cnt[k], hist[k]);
}

__global__ void k_bucket_scan(const int* __restrict__ bucket_cnt,
                              int* __restrict__ bucket_base,
                              int* __restrict__ bucket_cursor, int NB, int E) {
  __shared__ int sm[512];
  int t = threadIdx.x;
  int v = (t < NB) ? bucket_cnt[t] : 0;
  sm[t] = v;
  __syncthreads();
  for (int off = 1; off < 512; off <<= 1) {
    int add = (t >= off) ? sm[t - off] : 0;
    __syncthreads();
    sm[t] += add;
    __syncthreads();
  }
  int excl = sm[t] - v;
  if (t < NB) {
    bucket_base[t] = excl;
    bucket_cursor[t] = excl;
  }
  if (t == 0) bucket_base[NB] = E;
}

__global__ __launch_bounds__(256) void k_bucket_fill(
    const int* __restrict__ src, const int* __restrict__ dst,
    int* __restrict__ bucket_cursor, unsigned int* __restrict__ tmp,
    int E, int NB, int chunk) {
  __shared__ int hist[512];
  __shared__ int cur[512];
  int t = threadIdx.x;
  hist[t] = 0;
  hist[t + 256] = 0;
  __syncthreads();
  int beg = blockIdx.x * chunk, end = min(beg + chunk, E);
  for (int i = beg + t; i < end; i += 256) atomicAdd(&hist[dst[i] >> 8], 1);
  __syncthreads();
  for (int k = t; k < 512; k += 256)
    cur[k] = (k < NB && hist[k]) ? atomicAdd(&bucket_cursor[k], hist[k]) : 0;
  __syncthreads();
  for (int i = beg + t; i < end; i += 256) {
    int d = dst[i];
    int p = atomicAdd(&cur[d >> 8], 1);
    tmp[p] = (((unsigned int)(d & 255)) << 24) | (unsigned int)src[i];
  }
}

__global__ __launch_bounds__(256) void k_local_sort(
    const unsigned int* __restrict__ tmp, const int* __restrict__ bucket_base,
    int* __restrict__ csr, int* __restrict__ row_ptr, float* __restrict__ dinv,
    int N, int E) {
  __shared__ int cnt[256];
  __shared__ int scan_s[256];
  int b = blockIdx.x, t = threadIdx.x;
  int base = bucket_base[b];
  int cnt_b = bucket_base[b + 1] - base;
  cnt[t] = 0;
  __syncthreads();
  for (int i = t; i < cnt_b; i += 256) atomicAdd(&cnt[tmp[base + i] >> 24], 1);
  __syncthreads();
  int v = cnt[t];
  scan_s[t] = v;
  __syncthreads();
  for (int off = 1; off < 256; off <<= 1) {
    int add = (t >= off) ? scan_s[t - off] : 0;
    __syncthreads();
    scan_s[t] += add;
    __syncthreads();
  }
  int excl = scan_s[t] - v;
  int node = b * 256 + t;
  if (node <= N) row_ptr[node] = base + excl;
  if (node < N) dinv[node] = (v > 0) ? (1.0f / (float)v) : 0.0f;
  __syncthreads();
  cnt[t] = base + excl;  // running cursor
  __syncthreads();
  for (int i = t; i < cnt_b; i += 256) {
    unsigned int u = tmp[base + i];
    int q = atomicAdd(&cnt[u >> 24], 1);
    csr[q] = (int)(u & 0x00FFFFFFu);
  }
}

// ------- merged setup: zero bucket_cnt + weights->bf16 + Wc + x->bf16 -------
__global__ __launch_bounds__(256) void k_setup(
    const float* __restrict__ w1l, const float* __restrict__ w1r,
    const float* __restrict__ w2l, const float* __restrict__ w2r,
    const float* __restrict__ W3l, const float* __restrict__ W3r,
    unsigned short* __restrict__ Wbf, unsigned short* __restrict__ Wc,
    const float* __restrict__ x, unsigned int* __restrict__ Xbf,
    int n_pairs, int* __restrict__ bucket_cnt, int do_x) {
  int gid = blockIdx.x * 256 + threadIdx.x;
  int gstride = gridDim.x * 256;
  if (gid < 512) bucket_cnt[gid] = 0;
  if (gid < 65536) {
    int m = gid >> 14, off = gid & 16383;
    const float* srcw = (m == 0) ? w1l : (m == 1) ? w1r : (m == 2) ? w2l : w2r;
    Wbf[gid] = f2bf(srcw[off]);
  }
  if (gid < 2048) {
    int r = gid >> 7, c = gid & 127;
    float v = 0.f;
    if (r < 7) v = W3l[r * NFEAT + c];
    else if (r >= 8 && r < 15) v = W3r[(r - 8) * NFEAT + c];
    Wc[gid] = f2bf(v);
  }
  if (do_x) {
    for (int i = gid; i < n_pairs; i += gstride) {
      float2 v = *(const float2*)(x + (size_t)i * 2);
      Xbf[i] = pack2(v.x, v.y);
    }
  }
}

// ---------------- mean aggregation, bf16, persistent grid-stride waves ----------------
// one node per wave per iteration; 4 edge-slots x 16 lanes x 16B; next node's
// row_ptr prefetched one iteration ahead. __shfl only at full-wave points.
__global__ __launch_bounds__(256) void k_aggregate(
    const unsigned int* __restrict__ xp, const int* __restrict__ row_ptr,
    const int* __restrict__ csr, const float* __restrict__ dinv,
    unsigned int* __restrict__ Aout, int n) {
  int wv = threadIdx.x >> 6, lane = threadIdx.x & 63;
  int wave = blockIdx.x * 4 + wv;
  int stride = gridDim.x * 4;
  int slot = lane >> 4, part = lane & 15;

  int v = wave;
  if (v >= n) return;  // wave-uniform
  int nbeg = row_ptr[v], nend = row_ptr[v + 1];
  while (true) {
    int beg = nbeg, end = nend;
    int vn = v + stride;
    if (vn < n) {  // prefetch next node's range (overlaps current gather)
      nbeg = row_ptr[vn];
      nend = row_ptr[vn + 1];
    }
    int idx = 0;
    if (beg + lane < end) idx = csr[beg + lane];

    float acc[8] = {0.f, 0.f, 0.f, 0.f, 0.f, 0.f, 0.f, 0.f};
    for (int j = beg; j < end; j += 16) {
      int sidx[4];
#pragma unroll
      for (int b = 0; b < 4; ++b) {
        int rel = (j - beg) + b * 4 + slot;
        sidx[b] = __shfl(idx, rel & 63);  // all 64 lanes active here
      }
      uint4 f[4];
#pragma unroll
      for (int b = 0; b < 4; ++b) {
        f[b] = make_uint4(0u, 0u, 0u, 0u);
        int e = j + b * 4 + slot;
        if (e < end) {
          int rel = e - beg;
          int s = (rel < 64) ? sidx[b] : csr[e];
          f[b] = *(const uint4*)(xp + (size_t)s * (NFEAT / 2) + part * 4);
        }
      }
#pragma unroll
      for (int b = 0; b < 4; ++b) acc_uint4(acc, f[b]);
    }
#pragma unroll
    for (int k = 0; k < 8; ++k) {
      acc[k] += __shfl_xor(acc[k], 16);
      acc[k] += __shfl_xor(acc[k], 32);
    }
    if (slot == 0) {
      float dv = dinv[v];
      uint4 o;
      o.x = pack2(acc[0] * dv, acc[1] * dv);
      o.y = pack2(acc[2] * dv, acc[3] * dv);
      o.z = pack2(acc[4] * dv, acc[5] * dv);
      o.w = pack2(acc[6] * dv, acc[7] * dv);
      *(uint4*)(Aout + (size_t)v * (NFEAT / 2) + part * 4) = o;
    }
    if (vn >= n) break;  // wave-uniform
    v = vn;
  }
}

// ---------------- fp32-input aggregate (fallback only) ----------------
__global__ __launch_bounds__(256) void k_aggregate_f32(
    const float* __restrict__ xp, const int* __restrict__ row_ptr,
    const int* __restrict__ csr, const float* __restrict__ dinv,
    unsigned int* __restrict__ Aout, int n) {
  int wv = threadIdx.x >> 6, lane = threadIdx.x & 63;
  int v = blockIdx.x * 4 + wv;
  if (v >= n) return;
  int beg = row_ptr[v], end = row_ptr[v + 1];
  float dv = dinv[v];
  int slot = lane >> 5;
  int part = lane & 31;
  float acc[4] = {0.f, 0.f, 0.f, 0.f};
  for (int j = beg; j < end; j += 16) {
    float4 f[8];
#pragma unroll
    for (int b = 0; b < 8; ++b) {
      f[b] = make_float4(0.f, 0.f, 0.f, 0.f);
      int e = j + b * 2 + slot;
      if (e < end) {
        int si = csr[e];
        f[b] = *(const float4*)(xp + (size_t)si * NFEAT + part * 4);
      }
    }
#pragma unroll
    for (int b = 0; b < 8; ++b) {
      acc[0] += f[b].x; acc[1] += f[b].y; acc[2] += f[b].z; acc[3] += f[b].w;
    }
  }
#pragma unroll
  for (int k = 0; k < 4; ++k) acc[k] += __shfl_xor(acc[k], 32);
  if (slot == 0) {
    uint2 o;
    o.x = pack2(acc[0] * dv, acc[1] * dv);
    o.y = pack2(acc[2] * dv, acc[3] * dv);
    *(uint2*)(Aout + (size_t)v * (NFEAT / 2) + part * 2) = o;
  }
}

// ---------------- fused dual GEMM: Out = relu(A@Wl.T + bias + X@Wr.T) ----------------
template <bool X_IS_F32, bool INPLACE>
__global__ __launch_bounds__(256, 4) void k_gemm(
    const unsigned short* __restrict__ A, const void* __restrict__ X,
    const unsigned short* __restrict__ Wl, const unsigned short* __restrict__ Wr,
    const float* __restrict__ bias, unsigned short* __restrict__ Out,
    int M, int ntiles) {
  int wv = threadIdx.x >> 6, lane = threadIdx.x & 63;
  int lr = lane & 15, kq = lane >> 4;
  int kb0 = kq * 8;

  frag8 wl[2][4], wr[2][4];
  float bias_c[2];
#pragma unroll
  for (int ci = 0; ci < 2; ++ci) {
    int wrow = (wv * 2 + ci) * 16 + lr;
    bias_c[ci] = bias[wrow];
#pragma unroll
    for (int kk = 0; kk < 4; ++kk) {
      wl[ci][kk] = *(const frag8*)(Wl + (size_t)wrow * NFEAT + kk * 32 + kb0);
      wr[ci][kk] = *(const frag8*)(Wr + (size_t)wrow * NFEAT + kk * 32 + kb0);
    }
  }

  for (int tile = blockIdx.x; tile < ntiles; tile += gridDim.x) {
    int m0 = tile * 16;
    int row = m0 + lr;
    bool rowok = row < M;
    frag8 aA[4], aX[4];
#pragma unroll
    for (int kk = 0; kk < 4; ++kk) {
      aA[kk] = frag8{};
      aX[kk] = frag8{};
      if (rowok) {
        aA[kk] = *(const frag8*)(A + (size_t)row * NFEAT + kk * 32 + kb0);
        if constexpr (X_IS_F32) {
          const float* xp = (const float*)X + (size_t)row * NFEAT + kk * 32 + kb0;
          float4 v0 = *(const float4*)xp;
          float4 v1 = *(const float4*)(xp + 4);
          frag8 a;
          a[0] = (short)f2bf(v0.x); a[1] = (short)f2bf(v0.y);
          a[2] = (short)f2bf(v0.z); a[3] = (short)f2bf(v0.w);
          a[4] = (short)f2bf(v1.x); a[5] = (short)f2bf(v1.y);
          a[6] = (short)f2bf(v1.z); a[7] = (short)f2bf(v1.w);
          aX[kk] = a;
        } else {
          aX[kk] = *(const frag8*)((const unsigned short*)X + (size_t)row * NFEAT + kk * 32 + kb0);
        }
      }
    }
    if constexpr (INPLACE) __syncthreads();  // reads done before in-place writes
    f32x4 acc[2] = {};
#pragma unroll
    for (int kk = 0; kk < 4; ++kk) {
#pragma unroll
      for (int ci = 0; ci < 2; ++ci) {
        acc[ci] = __builtin_amdgcn_mfma_f32_16x16x32_bf16(aA[kk], wl[ci][kk], acc[ci], 0, 0, 0);
        acc[ci] = __builtin_amdgcn_mfma_f32_16x16x32_bf16(aX[kk], wr[ci][kk], acc[ci], 0, 0, 0);
      }
    }
#pragma unroll
    for (int ci = 0; ci < 2; ++ci) {
#pragma unroll
      for (int r = 0; r < 4; ++r) {
        int orow = m0 + kq * 4 + r;
        if (orow < M) {
          int ocol = (wv * 2 + ci) * 16 + lr;
          float val = acc[ci][r] + bias_c[ci];
          Out[(size_t)orow * NFEAT + ocol] = f2bf(fmaxf(val, 0.f));
        }
      }
    }
  }
}

// ------- layer-3 projection via MFMA: [p|q] = h2 @ [W3l;W3r].T (skinny GEMM) -------
__global__ __launch_bounds__(256) void k_proj7m(
    const unsigned short* __restrict__ H, const unsigned short* __restrict__ Wc,
    float* __restrict__ P, float* __restrict__ Q, int M, int ntiles) {
  int wv = threadIdx.x >> 6, lane = threadIdx.x & 63;
  int lr = lane & 15, kq = lane >> 4;
  int kb0 = kq * 8;
  frag8 wb[4];
#pragma unroll
  for (int kk = 0; kk < 4; ++kk)
    wb[kk] = *(const frag8*)(Wc + (size_t)lr * NFEAT + kk * 32 + kb0);

  int tile = blockIdx.x * 4 + wv;
  if (tile >= ntiles) return;
  int m0 = tile * 16;
  int row = m0 + lr;
  bool rowok = row < M;
  frag8 a[4];
#pragma unroll
  for (int kk = 0; kk < 4; ++kk) {
    a[kk] = frag8{};
    if (rowok) a[kk] = *(const frag8*)(H + (size_t)row * NFEAT + kk * 32 + kb0);
  }
  f32x4 acc = {};
#pragma unroll
  for (int kk = 0; kk < 4; ++kk)
    acc = __builtin_amdgcn_mfma_f32_16x16x32_bf16(a[kk], wb[kk], acc, 0, 0, 0);
#pragma unroll
  for (int r = 0; r < 4; ++r) {
    int orow = m0 + kq * 4 + r;
    if (orow < M) {
      if (lr < 8) P[(size_t)orow * 8 + lr] = acc[r];
      else Q[(size_t)orow * 8 + (lr - 8)] = acc[r];
    }
  }
}

// ------- layer 3: persistent grid-stride; agg_p gather + q + b3 + log_softmax -------
__global__ __launch_bounds__(256) void k_layer3s(
    const float* __restrict__ P, const float* __restrict__ Q,
    const int* __restrict__ row_ptr, const int* __restrict__ csr,
    const float* __restrict__ dinv, const float* __restrict__ b3,
    float* __restrict__ out, int n) {
  int wv = threadIdx.x >> 6, lane = threadIdx.x & 63;
  int wave = blockIdx.x * 4 + wv;
  int stride = gridDim.x * 4;
  int g = lane >> 3, c = lane & 7;

  int v = wave;
  if (v >= n) return;  // wave-uniform
  int nbeg = row_ptr[v], nend = row_ptr[v + 1];
  while (true) {
    int beg = nbeg, end = nend;
    int vn = v + stride;
    if (vn < n) {
      nbeg = row_ptr[vn];
      nend = row_ptr[vn + 1];
    }
    float acc = 0.f;
    for (int j = beg; j < end; j += 16) {
      float f0 = 0.f, f1 = 0.f;
      int e0 = j + g, e1 = j + 8 + g;
      if (e0 < end) f0 = P[(size_t)csr[e0] * 8 + c];
      if (e1 < end) f1 = P[(size_t)csr[e1] * 8 + c];
      acc += f0 + f1;
    }
    acc += __shfl_xor(acc, 8);
    acc += __shfl_xor(acc, 16);
    acc += __shfl_xor(acc, 32);
    float z_own = acc * dinv[v] + Q[(size_t)v * 8 + c] + ((c < 7) ? b3[c] : 0.f);
    float mx = -1e30f, se = 0.f;
    float zz[7];
#pragma unroll
    for (int cc = 0; cc < 7; ++cc) {
      zz[cc] = __shfl(z_own, cc);
      mx = fmaxf(mx, zz[cc]);
    }
#pragma unroll
    for (int cc = 0; cc < 7; ++cc) se += __expf(zz[cc] - mx);
    float lse = mx + __logf(se);
    if (lane < 7) out[(size_t)v * 7 + lane] = z_own - lse;
    if (vn >= n) break;  // wave-uniform
    v = vn;
  }
}

// ---------------- launch ----------------
extern "C" void kernel_launch(void* const* d_in, const int* in_sizes, int n_in,
                              void* d_out, int out_size, void* d_ws, size_t ws_size,
                              hipStream_t stream) {
  const float* x = (const float*)d_in[0];
  const int* ei = (const int*)d_in[1];
  const float* W1l = (const float*)d_in[2];
  const float* b1 = (const float*)d_in[3];
  const float* W1r = (const float*)d_in[4];
  const float* W2l = (const float*)d_in[5];
  const float* b2 = (const float*)d_in[6];
  const float* W2r = (const float*)d_in[7];
  const float* W3l = (const float*)d_in[8];
  const float* b3 = (const float*)d_in[9];
  const float* W3r = (const float*)d_in[10];
  float* out = (float*)d_out;

  int N = in_sizes[0] / NFEAT;
  int E = in_sizes[1] / 2;
  const int* src = ei;
  const int* dst = ei + E;

  char* ws = (char*)d_ws;
  size_t off = 0;
  auto alloc = [&](size_t bytes) {
    void* p = (void*)(ws + off);
    off += (bytes + 255) & ~(size_t)255;
    return p;
  };
  int* row_ptr = (int*)alloc((size_t)(N + 1) * 4);
  float* dinv = (float*)alloc((size_t)N * 4);
  int* bucket_cnt = (int*)alloc(512 * 4);
  int* bucket_base = (int*)alloc(513 * 4);
  int* bucket_cursor = (int*)alloc(512 * 4);
  int* csr = (int*)alloc((size_t)E * 4);
  unsigned short* Wbf = (unsigned short*)alloc((size_t)4 * 128 * 128 * 2);
  unsigned short* Wc = (unsigned short*)alloc((size_t)16 * 128 * 2);
  unsigned short* Abuf = (unsigned short*)alloc((size_t)N * NFEAT * 2);
  unsigned short* Bbuf = (unsigned short*)alloc((size_t)N * NFEAT * 2);
  size_t off_base = off;
  unsigned short* Xbf = (unsigned short*)alloc((size_t)N * NFEAT * 2);
  bool use_xbf = (off <= ws_size);
  if (!use_xbf) off = off_base;
  unsigned int* tmp = (unsigned int*)Abuf;  // aliased: only live during CSR build
  float* P = (float*)Abuf;                  // P/Q alias Abuf (dead after layer-2 GEMM)
  float* Q = P + (size_t)N * 8;

  int NB = (N + 255) >> 8;
  int chunk = (E + 255) / 256;
  int npairs = N * (NFEAT / 2);

  k_setup<<<2048, 256, 0, stream>>>(W1l, W1r, W2l, W2r, W3l, W3r, Wbf, Wc, x,
                                    (unsigned int*)Xbf, npairs, bucket_cnt,
                                    use_xbf ? 1 : 0);
  k_bucket_count<<<256, 256, 0, stream>>>(dst, bucket_cnt, E, NB, chunk);
  k_bucket_scan<<<1, 512, 0, stream>>>(bucket_cnt, bucket_base, bucket_cursor, NB, E);
  k_bucket_fill<<<256, 256, 0, stream>>>(src, dst, bucket_cursor, tmp, E, NB, chunk);
  k_local_sort<<<NB, 256, 0, stream>>>(tmp, bucket_base, csr, row_ptr, dinv, N, E);

  unsigned short* W1l_bf = Wbf;
  unsigned short* W1r_bf = Wbf + 16384;
  unsigned short* W2l_bf = Wbf + 32768;
  unsigned short* W2r_bf = Wbf + 49152;

  int gagg = 2048;  // persistent: 8192 waves = 32/CU, grid-stride over nodes
  int gnode = (N + 3) / 4;
  int ntiles = (N + 15) / 16;
  int ggemm = min(ntiles, 1024);

  if (use_xbf) {
    // layer 1
    k_aggregate<<<gagg, 256, 0, stream>>>((const unsigned int*)Xbf, row_ptr, csr, dinv,
                                          (unsigned int*)Abuf, N);
    k_gemm<false, false><<<ggemm, 256, 0, stream>>>(Abuf, Xbf, W1l_bf, W1r_bf, b1,
                                                    Bbuf, N, ntiles);
    // layer 2: h2 -> Xbf (x-copy dead now) => barrier-free GEMM
    k_aggregate<<<gagg, 256, 0, stream>>>((const unsigned int*)Bbuf, row_ptr, csr, dinv,
                                          (unsigned int*)Abuf, N);
    k_gemm<false, false><<<ggemm, 256, 0, stream>>>(Abuf, Bbuf, W2l_bf, W2r_bf, b2,
                                                    Xbf, N, ntiles);
    // layer 3: MFMA projection to 7-d, then tiny gather + softmax
    k_proj7m<<<(ntiles + 3) / 4, 256, 0, stream>>>(Xbf, Wc, P, Q, N, ntiles);
  } else {
    k_aggregate_f32<<<gnode, 256, 0, stream>>>(x, row_ptr, csr, dinv,
                                               (unsigned int*)Abuf, N);
    k_gemm<true, false><<<ggemm, 256, 0, stream>>>(Abuf, x, W1l_bf, W1r_bf, b1,
                                                   Bbuf, N, ntiles);
    k_aggregate<<<gagg, 256, 0, stream>>>((const unsigned int*)Bbuf, row_ptr, csr, dinv,
                                          (unsigned int*)Abuf, N);
    k_gemm<false, true><<<ggemm, 256, 0, stream>>>(Abuf, Bbuf, W2l_bf, W2r_bf, b2,
                                                   Bbuf, N, ntiles);
    k_proj7m<<<(ntiles + 3) / 4, 256, 0, stream>>>(Bbuf, Wc, P, Q, N, ntiles);
  }
  k_layer3s<<<2048, 256, 0, stream>>>(P, Q, row_ptr, csr, dinv, b3, out, N);
}

// Round 12
// 300.926 us; speedup vs baseline: 1.1195x; 1.1195x over previous
//
#include <hip/hip_runtime.h>
#include <hip/hip_bf16.h>

#define NFEAT 128

typedef __attribute__((ext_vector_type(8))) short frag8;
typedef __attribute__((ext_vector_type(4))) float f32x4;

__device__ __forceinline__ unsigned short f2bf(float f) {
  unsigned int u = __builtin_bit_cast(unsigned int, f);
  u += 0x7fffu + ((u >> 16) & 1u);
  return (unsigned short)(u >> 16);
}
__device__ __forceinline__ unsigned int pack2(float lo, float hi) {
  return (unsigned int)f2bf(lo) | ((unsigned int)f2bf(hi) << 16);
}
// accumulate 2 packed bf16: lo exact; hi uses raw bits (low 16 bits are a
// <=2^-8-relative mantissa perturbation, below the bf16 rounding already present)
__device__ __forceinline__ void acc_pair(float* acc, unsigned int u) {
  acc[0] += __builtin_bit_cast(float, u << 16);
  acc[1] += __builtin_bit_cast(float, u);
}
__device__ __forceinline__ void acc_uint4(float* a, const uint4& f) {
  acc_pair(a + 0, f.x);
  acc_pair(a + 2, f.y);
  acc_pair(a + 4, f.z);
  acc_pair(a + 6, f.w);
}

// ================= CSR build: two-level bucketed counting sort =================
__global__ __launch_bounds__(256) void k_bucket_count(
    const int* __restrict__ dst, int* __restrict__ bucket_cnt, int E, int NB, int chunk) {
  __shared__ int hist[512];
  int t = threadIdx.x;
  hist[t] = 0;
  hist[t + 256] = 0;
  __syncthreads();
  int beg = blockIdx.x * chunk, end = min(beg + chunk, E);
  for (int i = beg + t; i < end; i += 256) atomicAdd(&hist[dst[i] >> 8], 1);
  __syncthreads();
  for (int k = t; k < NB; k += 256)
    if (hist[k]) atomicAdd(&bucket_cnt[k], hist[k]);
}

__global__ void k_bucket_scan(const int* __restrict__ bucket_cnt,
                              int* __restrict__ bucket_base,
                              int* __restrict__ bucket_cursor, int NB, int E) {
  __shared__ int sm[512];
  int t = threadIdx.x;
  int v = (t < NB) ? bucket_cnt[t] : 0;
  sm[t] = v;
  __syncthreads();
  for (int off = 1; off < 512; off <<= 1) {
    int add = (t >= off) ? sm[t - off] : 0;
    __syncthreads();
    sm[t] += add;
    __syncthreads();
  }
  int excl = sm[t] - v;
  if (t < NB) {
    bucket_base[t] = excl;
    bucket_cursor[t] = excl;
  }
  if (t == 0) bucket_base[NB] = E;
}

__global__ __launch_bounds__(256) void k_bucket_fill(
    const int* __restrict__ src, const int* __restrict__ dst,
    int* __restrict__ bucket_cursor, unsigned int* __restrict__ tmp,
    int E, int NB, int chunk) {
  __shared__ int hist[512];
  __shared__ int cur[512];
  int t = threadIdx.x;
  hist[t] = 0;
  hist[t + 256] = 0;
  __syncthreads();
  int beg = blockIdx.x * chunk, end = min(beg + chunk, E);
  for (int i = beg + t; i < end; i += 256) atomicAdd(&hist[dst[i] >> 8], 1);
  __syncthreads();
  for (int k = t; k < 512; k += 256)
    cur[k] = (k < NB && hist[k]) ? atomicAdd(&bucket_cursor[k], hist[k]) : 0;
  __syncthreads();
  for (int i = beg + t; i < end; i += 256) {
    int d = dst[i];
    int p = atomicAdd(&cur[d >> 8], 1);
    tmp[p] = (((unsigned int)(d & 255)) << 24) | (unsigned int)src[i];
  }
}

__global__ __launch_bounds__(256) void k_local_sort(
    const unsigned int* __restrict__ tmp, const int* __restrict__ bucket_base,
    int* __restrict__ csr, int* __restrict__ row_ptr, float* __restrict__ dinv,
    int N, int E) {
  __shared__ int cnt[256];
  __shared__ int scan_s[256];
  int b = blockIdx.x, t = threadIdx.x;
  int base = bucket_base[b];
  int cnt_b = bucket_base[b + 1] - base;
  cnt[t] = 0;
  __syncthreads();
  for (int i = t; i < cnt_b; i += 256) atomicAdd(&cnt[tmp[base + i] >> 24], 1);
  __syncthreads();
  int v = cnt[t];
  scan_s[t] = v;
  __syncthreads();
  for (int off = 1; off < 256; off <<= 1) {
    int add = (t >= off) ? scan_s[t - off] : 0;
    __syncthreads();
    scan_s[t] += add;
    __syncthreads();
  }
  int excl = scan_s[t] - v;
  int node = b * 256 + t;
  if (node <= N) row_ptr[node] = base + excl;
  if (node < N) dinv[node] = (v > 0) ? (1.0f / (float)v) : 0.0f;
  __syncthreads();
  cnt[t] = base + excl;  // running cursor
  __syncthreads();
  for (int i = t; i < cnt_b; i += 256) {
    unsigned int u = tmp[base + i];
    int q = atomicAdd(&cnt[u >> 24], 1);
    csr[q] = (int)(u & 0x00FFFFFFu);
  }
}

// ------- merged setup: zero bucket_cnt + weights->bf16 + Wc + x->bf16 -------
__global__ __launch_bounds__(256) void k_setup(
    const float* __restrict__ w1l, const float* __restrict__ w1r,
    const float* __restrict__ w2l, const float* __restrict__ w2r,
    const float* __restrict__ W3l, const float* __restrict__ W3r,
    unsigned short* __restrict__ Wbf, unsigned short* __restrict__ Wc,
    const float* __restrict__ x, unsigned int* __restrict__ Xbf,
    int n_pairs, int* __restrict__ bucket_cnt, int do_x) {
  int gid = blockIdx.x * 256 + threadIdx.x;
  int gstride = gridDim.x * 256;
  if (gid < 512) bucket_cnt[gid] = 0;
  if (gid < 65536) {
    int m = gid >> 14, off = gid & 16383;
    const float* srcw = (m == 0) ? w1l : (m == 1) ? w1r : (m == 2) ? w2l : w2r;
    Wbf[gid] = f2bf(srcw[off]);
  }
  if (gid < 2048) {
    int r = gid >> 7, c = gid & 127;
    float v = 0.f;
    if (r < 7) v = W3l[r * NFEAT + c];
    else if (r >= 8 && r < 15) v = W3r[(r - 8) * NFEAT + c];
    Wc[gid] = f2bf(v);
  }
  if (do_x) {
    for (int i = gid; i < n_pairs; i += gstride) {
      float2 v = *(const float2*)(x + (size_t)i * 2);
      Xbf[i] = pack2(v.x, v.y);
    }
  }
}

// ---------------- mean aggregation, bf16 input, one node per wave ----------------
// 4 edge-slots x 16 lanes x 16B; 16 gathers in flight. <=64 indices preloaded with
// one coalesced csr read; per-edge index via UNCONDITIONAL __shfl (divergent-exec
// shfl was round-8's bug). deg>64 falls back to direct csr[e].
__global__ __launch_bounds__(256) void k_aggregate(
    const unsigned int* __restrict__ xp, const int* __restrict__ row_ptr,
    const int* __restrict__ csr, const float* __restrict__ dinv,
    unsigned int* __restrict__ Aout, int n) {
  int wv = threadIdx.x >> 6, lane = threadIdx.x & 63;
  int v = blockIdx.x * 4 + wv;
  if (v >= n) return;  // wave-uniform
  int beg = row_ptr[v], end = row_ptr[v + 1];
  float dv = dinv[v];
  int slot = lane >> 4, part = lane & 15;

  int idx = 0;
  if (beg + lane < end) idx = csr[beg + lane];

  float acc[8] = {0.f, 0.f, 0.f, 0.f, 0.f, 0.f, 0.f, 0.f};
  for (int j = beg; j < end; j += 16) {
    int sidx[4];
#pragma unroll
    for (int b = 0; b < 4; ++b) {
      int rel = (j - beg) + b * 4 + slot;
      sidx[b] = __shfl(idx, rel & 63);  // all 64 lanes active here
    }
    uint4 f[4];
#pragma unroll
    for (int b = 0; b < 4; ++b) {
      f[b] = make_uint4(0u, 0u, 0u, 0u);
      int e = j + b * 4 + slot;
      if (e < end) {
        int rel = e - beg;
        int s = (rel < 64) ? sidx[b] : csr[e];
        f[b] = *(const uint4*)(xp + (size_t)s * (NFEAT / 2) + part * 4);
      }
    }
#pragma unroll
    for (int b = 0; b < 4; ++b) acc_uint4(acc, f[b]);
  }
#pragma unroll
  for (int k = 0; k < 8; ++k) {
    acc[k] += __shfl_xor(acc[k], 16);
    acc[k] += __shfl_xor(acc[k], 32);
  }
  if (slot == 0) {
    uint4 o;
    o.x = pack2(acc[0] * dv, acc[1] * dv);
    o.y = pack2(acc[2] * dv, acc[3] * dv);
    o.z = pack2(acc[4] * dv, acc[5] * dv);
    o.w = pack2(acc[6] * dv, acc[7] * dv);
    *(uint4*)(Aout + (size_t)v * (NFEAT / 2) + part * 4) = o;
  }
}

// ---------------- fp32-input aggregate (fallback only) ----------------
__global__ __launch_bounds__(256) void k_aggregate_f32(
    const float* __restrict__ xp, const int* __restrict__ row_ptr,
    const int* __restrict__ csr, const float* __restrict__ dinv,
    unsigned int* __restrict__ Aout, int n) {
  int wv = threadIdx.x >> 6, lane = threadIdx.x & 63;
  int v = blockIdx.x * 4 + wv;
  if (v >= n) return;
  int beg = row_ptr[v], end = row_ptr[v + 1];
  float dv = dinv[v];
  int slot = lane >> 5;
  int part = lane & 31;
  float acc[4] = {0.f, 0.f, 0.f, 0.f};
  for (int j = beg; j < end; j += 16) {
    float4 f[8];
#pragma unroll
    for (int b = 0; b < 8; ++b) {
      f[b] = make_float4(0.f, 0.f, 0.f, 0.f);
      int e = j + b * 2 + slot;
      if (e < end) {
        int si = csr[e];
        f[b] = *(const float4*)(xp + (size_t)si * NFEAT + part * 4);
      }
    }
#pragma unroll
    for (int b = 0; b < 8; ++b) {
      acc[0] += f[b].x; acc[1] += f[b].y; acc[2] += f[b].z; acc[3] += f[b].w;
    }
  }
#pragma unroll
  for (int k = 0; k < 4; ++k) acc[k] += __shfl_xor(acc[k], 32);
  if (slot == 0) {
    uint2 o;
    o.x = pack2(acc[0] * dv, acc[1] * dv);
    o.y = pack2(acc[2] * dv, acc[3] * dv);
    *(uint2*)(Aout + (size_t)v * (NFEAT / 2) + part * 2) = o;
  }
}

// ---------------- fused dual GEMM: Out = relu(A@Wl.T + bias + X@Wr.T) ----------------
template <bool X_IS_F32, bool INPLACE>
__global__ __launch_bounds__(256, 4) void k_gemm(
    const unsigned short* __restrict__ A, const void* __restrict__ X,
    const unsigned short* __restrict__ Wl, const unsigned short* __restrict__ Wr,
    const float* __restrict__ bias, unsigned short* __restrict__ Out,
    int M, int ntiles) {
  int wv = threadIdx.x >> 6, lane = threadIdx.x & 63;
  int lr = lane & 15, kq = lane >> 4;
  int kb0 = kq * 8;

  frag8 wl[2][4], wr[2][4];
  float bias_c[2];
#pragma unroll
  for (int ci = 0; ci < 2; ++ci) {
    int wrow = (wv * 2 + ci) * 16 + lr;
    bias_c[ci] = bias[wrow];
#pragma unroll
    for (int kk = 0; kk < 4; ++kk) {
      wl[ci][kk] = *(const frag8*)(Wl + (size_t)wrow * NFEAT + kk * 32 + kb0);
      wr[ci][kk] = *(const frag8*)(Wr + (size_t)wrow * NFEAT + kk * 32 + kb0);
    }
  }

  for (int tile = blockIdx.x; tile < ntiles; tile += gridDim.x) {
    int m0 = tile * 16;
    int row = m0 + lr;
    bool rowok = row < M;
    frag8 aA[4], aX[4];
#pragma unroll
    for (int kk = 0; kk < 4; ++kk) {
      aA[kk] = frag8{};
      aX[kk] = frag8{};
      if (rowok) {
        aA[kk] = *(const frag8*)(A + (size_t)row * NFEAT + kk * 32 + kb0);
        if constexpr (X_IS_F32) {
          const float* xp = (const float*)X + (size_t)row * NFEAT + kk * 32 + kb0;
          float4 v0 = *(const float4*)xp;
          float4 v1 = *(const float4*)(xp + 4);
          frag8 a;
          a[0] = (short)f2bf(v0.x); a[1] = (short)f2bf(v0.y);
          a[2] = (short)f2bf(v0.z); a[3] = (short)f2bf(v0.w);
          a[4] = (short)f2bf(v1.x); a[5] = (short)f2bf(v1.y);
          a[6] = (short)f2bf(v1.z); a[7] = (short)f2bf(v1.w);
          aX[kk] = a;
        } else {
          aX[kk] = *(const frag8*)((const unsigned short*)X + (size_t)row * NFEAT + kk * 32 + kb0);
        }
      }
    }
    if constexpr (INPLACE) __syncthreads();  // reads done before in-place writes
    f32x4 acc[2] = {};
#pragma unroll
    for (int kk = 0; kk < 4; ++kk) {
#pragma unroll
      for (int ci = 0; ci < 2; ++ci) {
        acc[ci] = __builtin_amdgcn_mfma_f32_16x16x32_bf16(aA[kk], wl[ci][kk], acc[ci], 0, 0, 0);
        acc[ci] = __builtin_amdgcn_mfma_f32_16x16x32_bf16(aX[kk], wr[ci][kk], acc[ci], 0, 0, 0);
      }
    }
#pragma unroll
    for (int ci = 0; ci < 2; ++ci) {
#pragma unroll
      for (int r = 0; r < 4; ++r) {
        int orow = m0 + kq * 4 + r;
        if (orow < M) {
          int ocol = (wv * 2 + ci) * 16 + lr;
          float val = acc[ci][r] + bias_c[ci];
          Out[(size_t)orow * NFEAT + ocol] = f2bf(fmaxf(val, 0.f));
        }
      }
    }
  }
}

// ------- layer-3 projection via MFMA: [p|q] = h2 @ [W3l;W3r].T (skinny GEMM) -------
__global__ __launch_bounds__(256) void k_proj7m(
    const unsigned short* __restrict__ H, const unsigned short* __restrict__ Wc,
    float* __restrict__ P, float* __restrict__ Q, int M, int ntiles) {
  int wv = threadIdx.x >> 6, lane = threadIdx.x & 63;
  int lr = lane & 15, kq = lane >> 4;
  int kb0 = kq * 8;
  frag8 wb[4];
#pragma unroll
  for (int kk = 0; kk < 4; ++kk)
    wb[kk] = *(const frag8*)(Wc + (size_t)lr * NFEAT + kk * 32 + kb0);

  int tile = blockIdx.x * 4 + wv;
  if (tile >= ntiles) return;
  int m0 = tile * 16;
  int row = m0 + lr;
  bool rowok = row < M;
  frag8 a[4];
#pragma unroll
  for (int kk = 0; kk < 4; ++kk) {
    a[kk] = frag8{};
    if (rowok) a[kk] = *(const frag8*)(H + (size_t)row * NFEAT + kk * 32 + kb0);
  }
  f32x4 acc = {};
#pragma unroll
  for (int kk = 0; kk < 4; ++kk)
    acc = __builtin_amdgcn_mfma_f32_16x16x32_bf16(a[kk], wb[kk], acc, 0, 0, 0);
#pragma unroll
  for (int r = 0; r < 4; ++r) {
    int orow = m0 + kq * 4 + r;
    if (orow < M) {
      if (lr < 8) P[(size_t)orow * 8 + lr] = acc[r];
      else Q[(size_t)orow * 8 + (lr - 8)] = acc[r];
    }
  }
}

// ------- layer 3: agg_p gather (32B/edge, L2-resident P) + q + b3 + log_softmax -------
__global__ __launch_bounds__(256) void k_layer3s(
    const float* __restrict__ P, const float* __restrict__ Q,
    const int* __restrict__ row_ptr, const int* __restrict__ csr,
    const float* __restrict__ dinv, const float* __restrict__ b3,
    float* __restrict__ out, int n) {
  int wv = threadIdx.x >> 6, lane = threadIdx.x & 63;
  int v = blockIdx.x * 4 + wv;
  if (v >= n) return;
  int beg = row_ptr[v], end = row_ptr[v + 1];
  int g = lane >> 3, c = lane & 7;
  float acc = 0.f;
  for (int j = beg; j < end; j += 16) {
    float f0 = 0.f, f1 = 0.f;
    int e0 = j + g, e1 = j + 8 + g;
    if (e0 < end) f0 = P[(size_t)csr[e0] * 8 + c];
    if (e1 < end) f1 = P[(size_t)csr[e1] * 8 + c];
    acc += f0 + f1;
  }
  acc += __shfl_xor(acc, 8);
  acc += __shfl_xor(acc, 16);
  acc += __shfl_xor(acc, 32);
  float z_own = acc * dinv[v] + Q[(size_t)v * 8 + c] + ((c < 7) ? b3[c] : 0.f);
  float mx = -1e30f, se = 0.f;
  float zz[7];
#pragma unroll
  for (int cc = 0; cc < 7; ++cc) {
    zz[cc] = __shfl(z_own, cc);
    mx = fmaxf(mx, zz[cc]);
  }
#pragma unroll
  for (int cc = 0; cc < 7; ++cc) se += __expf(zz[cc] - mx);
  float lse = mx + __logf(se);
  if (lane < 7) out[(size_t)v * 7 + lane] = z_own - lse;
}

// ---------------- launch ----------------
extern "C" void kernel_launch(void* const* d_in, const int* in_sizes, int n_in,
                              void* d_out, int out_size, void* d_ws, size_t ws_size,
                              hipStream_t stream) {
  const float* x = (const float*)d_in[0];
  const int* ei = (const int*)d_in[1];
  const float* W1l = (const float*)d_in[2];
  const float* b1 = (const float*)d_in[3];
  const float* W1r = (const float*)d_in[4];
  const float* W2l = (const float*)d_in[5];
  const float* b2 = (const float*)d_in[6];
  const float* W2r = (const float*)d_in[7];
  const float* W3l = (const float*)d_in[8];
  const float* b3 = (const float*)d_in[9];
  const float* W3r = (const float*)d_in[10];
  float* out = (float*)d_out;

  int N = in_sizes[0] / NFEAT;
  int E = in_sizes[1] / 2;
  const int* src = ei;
  const int* dst = ei + E;

  char* ws = (char*)d_ws;
  size_t off = 0;
  auto alloc = [&](size_t bytes) {
    void* p = (void*)(ws + off);
    off += (bytes + 255) & ~(size_t)255;
    return p;
  };
  int* row_ptr = (int*)alloc((size_t)(N + 1) * 4);
  float* dinv = (float*)alloc((size_t)N * 4);
  int* bucket_cnt = (int*)alloc(512 * 4);
  int* bucket_base = (int*)alloc(513 * 4);
  int* bucket_cursor = (int*)alloc(512 * 4);
  int* csr = (int*)alloc((size_t)E * 4);
  unsigned short* Wbf = (unsigned short*)alloc((size_t)4 * 128 * 128 * 2);
  unsigned short* Wc = (unsigned short*)alloc((size_t)16 * 128 * 2);
  unsigned short* Abuf = (unsigned short*)alloc((size_t)N * NFEAT * 2);
  unsigned short* Bbuf = (unsigned short*)alloc((size_t)N * NFEAT * 2);
  size_t off_base = off;
  unsigned short* Xbf = (unsigned short*)alloc((size_t)N * NFEAT * 2);
  bool use_xbf = (off <= ws_size);
  if (!use_xbf) off = off_base;
  unsigned int* tmp = (unsigned int*)Abuf;  // aliased: only live during CSR build
  float* P = (float*)Abuf;                  // P/Q alias Abuf (dead after layer-2 GEMM)
  float* Q = P + (size_t)N * 8;

  int NB = (N + 255) >> 8;
  int chunk = (E + 255) / 256;
  int npairs = N * (NFEAT / 2);

  k_setup<<<2048, 256, 0, stream>>>(W1l, W1r, W2l, W2r, W3l, W3r, Wbf, Wc, x,
                                    (unsigned int*)Xbf, npairs, bucket_cnt,
                                    use_xbf ? 1 : 0);
  k_bucket_count<<<256, 256, 0, stream>>>(dst, bucket_cnt, E, NB, chunk);
  k_bucket_scan<<<1, 512, 0, stream>>>(bucket_cnt, bucket_base, bucket_cursor, NB, E);
  k_bucket_fill<<<256, 256, 0, stream>>>(src, dst, bucket_cursor, tmp, E, NB, chunk);
  k_local_sort<<<NB, 256, 0, stream>>>(tmp, bucket_base, csr, row_ptr, dinv, N, E);

  unsigned short* W1l_bf = Wbf;
  unsigned short* W1r_bf = Wbf + 16384;
  unsigned short* W2l_bf = Wbf + 32768;
  unsigned short* W2r_bf = Wbf + 49152;

  int gnode = (N + 3) / 4;  // 1 node/wave, 4 waves/block (block order = node order)
  int ntiles = (N + 15) / 16;
  int ggemm = min(ntiles, 1024);

  if (use_xbf) {
    // layer 1
    k_aggregate<<<gnode, 256, 0, stream>>>((const unsigned int*)Xbf, row_ptr, csr, dinv,
                                           (unsigned int*)Abuf, N);
    k_gemm<false, false><<<ggemm, 256, 0, stream>>>(Abuf, Xbf, W1l_bf, W1r_bf, b1,
                                                    Bbuf, N, ntiles);
    // layer 2: h2 -> Xbf (x-copy dead now) => barrier-free GEMM
    k_aggregate<<<gnode, 256, 0, stream>>>((const unsigned int*)Bbuf, row_ptr, csr, dinv,
                                           (unsigned int*)Abuf, N);
    k_gemm<false, false><<<ggemm, 256, 0, stream>>>(Abuf, Bbuf, W2l_bf, W2r_bf, b2,
                                                    Xbf, N, ntiles);
    // layer 3: MFMA projection to 7-d, then tiny gather + softmax
    k_proj7m<<<(ntiles + 3) / 4, 256, 0, stream>>>(Xbf, Wc, P, Q, N, ntiles);
  } else {
    k_aggregate_f32<<<gnode, 256, 0, stream>>>(x, row_ptr, csr, dinv,
                                               (unsigned int*)Abuf, N);
    k_gemm<true, false><<<ggemm, 256, 0, stream>>>(Abuf, x, W1l_bf, W1r_bf, b1,
                                                   Bbuf, N, ntiles);
    k_aggregate<<<gnode, 256, 0, stream>>>((const unsigned int*)Bbuf, row_ptr, csr, dinv,
                                           (unsigned int*)Abuf, N);
    k_gemm<false, true><<<ggemm, 256, 0, stream>>>(Abuf, Bbuf, W2l_bf, W2r_bf, b2,
                                                   Bbuf, N, ntiles);
    k_proj7m<<<(ntiles + 3) / 4, 256, 0, stream>>>(Bbuf, Wc, P, Q, N, ntiles);
  }
  k_layer3s<<<gnode, 256, 0, stream>>>(P, Q, row_ptr, csr, dinv, b3, out, N);
}